// Round 1
// baseline (494.806 us; speedup 1.0000x reference)
//
#include <hip/hip_runtime.h>
#include <hip/hip_bf16.h>
#include <cstdint>
#include <cstddef>

// Problem constants (fixed by the reference)
#define TDIM 1024
#define HDIM 1024
#define FDIM 2048
#define NEXP 8
#define NENT 2048   // T * K

typedef __bf16 bf16_t;
typedef __bf16 bf16x4 __attribute__((ext_vector_type(4)));
typedef __bf16 bf16x8 __attribute__((ext_vector_type(8)));
typedef float  f32x4  __attribute__((ext_vector_type(4)));

// ---------------- workspace layout (bytes) ----------------
// [0,32)   counts[8]
// [32,64)  counts2[8]
// [64,128) offsets[9]
// [128, +8KB) entry_token[2048]
// [.., +8KB)  entry_scale[2048]
// [16512, +8MB) act bf16[2048*2048]
#define WS_COUNTS   0
#define WS_COUNTS2  32
#define WS_OFFSETS  64
#define WS_ETOK     128
#define WS_ESCALE   (WS_ETOK + NENT*4)
#define WS_ACT      (WS_ESCALE + NENT*4)

// ---------------- routing ----------------
__global__ void route_count(const int* __restrict__ sel, int* __restrict__ counts) {
  int i = blockIdx.x*256 + threadIdx.x;
  if (i < NENT) atomicAdd(&counts[sel[i]], 1);
}

__global__ void route_scan(const int* __restrict__ counts, int* __restrict__ offsets) {
  if (threadIdx.x == 0) {
    int s = 0;
    for (int e = 0; e < NEXP; e++) { offsets[e] = s; s += counts[e]; }
    offsets[NEXP] = s;
  }
}

__global__ void route_fill(const int* __restrict__ sel, const float* __restrict__ scal,
                           const int* __restrict__ offsets, int* __restrict__ counts2,
                           int* __restrict__ etok, float* __restrict__ escale) {
  int i = blockIdx.x*256 + threadIdx.x;
  if (i < NENT) {
    int e = sel[i];
    int pos = offsets[e] + atomicAdd(&counts2[e], 1);
    etok[pos]   = i >> 1;     // TOPK == 2
    escale[pos] = scal[i];
  }
}

// ---------------- grouped GEMM config ----------------
#define BM 128
#define BN 64
#define BK 32
#define LSTR 40   // 32 + 8 pad (bf16 elems); row stride 80B -> 16B aligned, ~2-way banks

// GEMM1: act = silu(x@w1g^T + b1g) * (x@w1l^T + b1l), per expert, gathered tokens.
__global__ __launch_bounds__(256, 2) void gemm1_kernel(
    const float* __restrict__ hidden, const float* __restrict__ w1,
    const float* __restrict__ b1, const int* __restrict__ offsets,
    const int* __restrict__ etok, bf16_t* __restrict__ act)
{
  const int e   = blockIdx.z;
  const int off = offsets[e];
  const int nt  = offsets[e+1] - off;
  const int m0  = blockIdx.y * BM;
  if (m0 >= nt) return;
  const int n0  = blockIdx.x * BN;

  __shared__ bf16_t As[BM*LSTR];
  __shared__ bf16_t Bg[BN*LSTR];
  __shared__ bf16_t Bl[BN*LSTR];

  const int tid = threadIdx.x;

  // A loader: 128 rows x 32 cols fp32, 16 floats/thread
  const int arow  = tid >> 1;
  const int ahalf = tid & 1;
  int aent = m0 + arow; if (aent > nt-1) aent = nt-1;   // clamp (rows >= nt masked in epilogue)
  const int atok = etok[off + aent];
  const float* aptr = hidden + (size_t)atok*HDIM + ahalf*16;

  // B loaders: 64 rows x 32 cols fp32 each (gate, lin), 8 floats/thread each
  const int brow = tid >> 2;
  const int bq   = tid & 3;
  const float* gptr = w1 + ((size_t)e*2*FDIM + (size_t)(n0 + brow))*HDIM + bq*8;
  const float* lptr = gptr + (size_t)FDIM*HDIM;

  const int wave = tid >> 6, lane = tid & 63;
  const int wr = wave >> 1, wc = wave & 1;
  const int quad = lane >> 4, lr = lane & 15;

  f32x4 accg[4][2] = {};
  f32x4 accl[4][2] = {};

  for (int k0 = 0; k0 < HDIM; k0 += BK) {
    float4 a4[4], g4[2], l4[2];
    const float4* ap = (const float4*)(aptr + k0);
    a4[0] = ap[0]; a4[1] = ap[1]; a4[2] = ap[2]; a4[3] = ap[3];
    const float4* gp = (const float4*)(gptr + k0);
    g4[0] = gp[0]; g4[1] = gp[1];
    const float4* lp = (const float4*)(lptr + k0);
    l4[0] = lp[0]; l4[1] = lp[1];

    __syncthreads();   // previous iteration's fragment reads complete
    {
      bf16_t* as = &As[arow*LSTR + ahalf*16];
      #pragma unroll
      for (int q = 0; q < 4; q++) {
        bf16x4 v; v[0]=(bf16_t)a4[q].x; v[1]=(bf16_t)a4[q].y; v[2]=(bf16_t)a4[q].z; v[3]=(bf16_t)a4[q].w;
        *(bf16x4*)(as + q*4) = v;
      }
      bf16_t* bg = &Bg[brow*LSTR + bq*8];
      #pragma unroll
      for (int q = 0; q < 2; q++) {
        bf16x4 v; v[0]=(bf16_t)g4[q].x; v[1]=(bf16_t)g4[q].y; v[2]=(bf16_t)g4[q].z; v[3]=(bf16_t)g4[q].w;
        *(bf16x4*)(bg + q*4) = v;
      }
      bf16_t* bl = &Bl[brow*LSTR + bq*8];
      #pragma unroll
      for (int q = 0; q < 2; q++) {
        bf16x4 v; v[0]=(bf16_t)l4[q].x; v[1]=(bf16_t)l4[q].y; v[2]=(bf16_t)l4[q].z; v[3]=(bf16_t)l4[q].w;
        *(bf16x4*)(bl + q*4) = v;
      }
    }
    __syncthreads();

    bf16x8 af[4], gf[2], lf[2];
    #pragma unroll
    for (int i = 0; i < 4; i++)
      af[i] = *(const bf16x8*)&As[(wr*64 + i*16 + lr)*LSTR + quad*8];
    #pragma unroll
    for (int j = 0; j < 2; j++) {
      gf[j] = *(const bf16x8*)&Bg[(wc*32 + j*16 + lr)*LSTR + quad*8];
      lf[j] = *(const bf16x8*)&Bl[(wc*32 + j*16 + lr)*LSTR + quad*8];
    }
    #pragma unroll
    for (int i = 0; i < 4; i++)
      #pragma unroll
      for (int j = 0; j < 2; j++) {
        accg[i][j] = __builtin_amdgcn_mfma_f32_16x16x32_bf16(af[i], gf[j], accg[i][j], 0, 0, 0);
        accl[i][j] = __builtin_amdgcn_mfma_f32_16x16x32_bf16(af[i], lf[j], accl[i][j], 0, 0, 0);
      }
  }

  // epilogue: bias + silu(gate)*lin -> act (bf16)
  #pragma unroll
  for (int j = 0; j < 2; j++) {
    const int f = n0 + wc*32 + j*16 + lr;
    const float bg_ = b1[e*2*FDIM + f];
    const float bl_ = b1[e*2*FDIM + FDIM + f];
    #pragma unroll
    for (int i = 0; i < 4; i++) {
      #pragma unroll
      for (int r = 0; r < 4; r++) {
        const int m = wr*64 + i*16 + quad*4 + r;
        if (m0 + m < nt) {
          const float g = accg[i][j][r] + bg_;
          const float l = accl[i][j][r] + bl_;
          const float s = g / (1.f + __expf(-g)) * l;
          act[(size_t)(off + m0 + m)*FDIM + f] = (bf16_t)s;
        }
      }
    }
  }
}

// GEMM2: y = act @ w2^T + b2; out[token] += scale * y  (atomic)
__global__ __launch_bounds__(256, 2) void gemm2_kernel(
    const bf16_t* __restrict__ act, const float* __restrict__ w2,
    const float* __restrict__ b2, const int* __restrict__ offsets,
    const int* __restrict__ etok, const float* __restrict__ escale,
    float* __restrict__ out)
{
  const int e   = blockIdx.z;
  const int off = offsets[e];
  const int nt  = offsets[e+1] - off;
  const int m0  = blockIdx.y * BM;
  if (m0 >= nt) return;
  const int n0  = blockIdx.x * BN;

  __shared__ bf16_t As[BM*LSTR];
  __shared__ bf16_t Bs[BN*LSTR];

  const int tid = threadIdx.x;

  // A loader: 128 rows x 32 cols bf16 (already bf16, direct copy)
  const int arow  = tid >> 1;
  const int ahalf = tid & 1;
  int aent = m0 + arow; if (aent > nt-1) aent = nt-1;
  const bf16_t* aptr = act + (size_t)(off + aent)*FDIM + ahalf*16;

  // B loader: 64 rows x 32 cols fp32
  const int brow = tid >> 2;
  const int bq   = tid & 3;
  const float* bptr = w2 + ((size_t)e*HDIM + (size_t)(n0 + brow))*FDIM + bq*8;

  const int wave = tid >> 6, lane = tid & 63;
  const int wr = wave >> 1, wc = wave & 1;
  const int quad = lane >> 4, lr = lane & 15;

  f32x4 acc[4][2] = {};

  for (int k0 = 0; k0 < FDIM; k0 += BK) {
    uint4 a0 = *(const uint4*)(aptr + k0);
    uint4 a1 = *(const uint4*)(aptr + k0 + 8);
    float4 b4[2];
    const float4* bp = (const float4*)(bptr + k0);
    b4[0] = bp[0]; b4[1] = bp[1];

    __syncthreads();
    {
      bf16_t* as = &As[arow*LSTR + ahalf*16];
      *(uint4*)(as)     = a0;
      *(uint4*)(as + 8) = a1;
      bf16_t* bs = &Bs[brow*LSTR + bq*8];
      #pragma unroll
      for (int q = 0; q < 2; q++) {
        bf16x4 v; v[0]=(bf16_t)b4[q].x; v[1]=(bf16_t)b4[q].y; v[2]=(bf16_t)b4[q].z; v[3]=(bf16_t)b4[q].w;
        *(bf16x4*)(bs + q*4) = v;
      }
    }
    __syncthreads();

    bf16x8 af[4], bf[2];
    #pragma unroll
    for (int i = 0; i < 4; i++)
      af[i] = *(const bf16x8*)&As[(wr*64 + i*16 + lr)*LSTR + quad*8];
    #pragma unroll
    for (int j = 0; j < 2; j++)
      bf[j] = *(const bf16x8*)&Bs[(wc*32 + j*16 + lr)*LSTR + quad*8];
    #pragma unroll
    for (int i = 0; i < 4; i++)
      #pragma unroll
      for (int j = 0; j < 2; j++)
        acc[i][j] = __builtin_amdgcn_mfma_f32_16x16x32_bf16(af[i], bf[j], acc[i][j], 0, 0, 0);
  }

  // epilogue: + b2, scale, atomic scatter-add into out
  #pragma unroll
  for (int i = 0; i < 4; i++) {
    #pragma unroll
    for (int r = 0; r < 4; r++) {
      const int m = wr*64 + i*16 + quad*4 + r;
      if (m0 + m < nt) {
        const int slot = off + m0 + m;
        const int t    = etok[slot];
        const float s  = escale[slot];
        #pragma unroll
        for (int j = 0; j < 2; j++) {
          const int n = n0 + wc*32 + j*16 + lr;
          atomicAdd(&out[(size_t)t*HDIM + n], s * (acc[i][j][r] + b2[e*HDIM + n]));
        }
      }
    }
  }
}

extern "C" void kernel_launch(void* const* d_in, const int* in_sizes, int n_in,
                              void* d_out, int out_size, void* d_ws, size_t ws_size,
                              hipStream_t stream) {
  const float* hidden = (const float*)d_in[0];
  const int*   sel    = (const int*)d_in[1];
  const float* scal   = (const float*)d_in[2];
  const float* w1     = (const float*)d_in[3];
  const float* b1     = (const float*)d_in[4];
  const float* w2     = (const float*)d_in[5];
  const float* b2     = (const float*)d_in[6];
  float* out = (float*)d_out;

  char* ws = (char*)d_ws;
  int*    counts  = (int*)(ws + WS_COUNTS);
  int*    counts2 = (int*)(ws + WS_COUNTS2);
  int*    offsets = (int*)(ws + WS_OFFSETS);
  int*    etok    = (int*)(ws + WS_ETOK);
  float*  escale  = (float*)(ws + WS_ESCALE);
  bf16_t* act     = (bf16_t*)(ws + WS_ACT);

  hipMemsetAsync(ws, 0, 64, stream);                                   // counts, counts2
  hipMemsetAsync(d_out, 0, (size_t)out_size * sizeof(float), stream);  // atomic accumulation target

  route_count<<<NENT/256, 256, 0, stream>>>(sel, counts);
  route_scan <<<1, 64, 0, stream>>>(counts, offsets);
  route_fill <<<NENT/256, 256, 0, stream>>>(sel, scal, offsets, counts2, etok, escale);

  gemm1_kernel<<<dim3(FDIM/BN, NENT/BM, NEXP), 256, 0, stream>>>(hidden, w1, b1, offsets, etok, act);
  gemm2_kernel<<<dim3(HDIM/BN, NENT/BM, NEXP), 256, 0, stream>>>(act, w2, b2, offsets, etok, escale, out);
}

// Round 2
// 361.349 us; speedup vs baseline: 1.3693x; 1.3693x over previous
//
#include <hip/hip_runtime.h>
#include <hip/hip_bf16.h>
#include <cstdint>
#include <cstddef>

// Problem constants (fixed by the reference)
#define TDIM 1024
#define HDIM 1024
#define FDIM 2048
#define NEXP 8
#define NENT 2048   // T * K

typedef __bf16 bf16_t;
typedef __bf16 bf16x4 __attribute__((ext_vector_type(4)));
typedef __bf16 bf16x8 __attribute__((ext_vector_type(8)));
typedef float  f32x4  __attribute__((ext_vector_type(4)));

// ---------------- workspace layout (bytes) ----------------
#define WS_COUNTS   0
#define WS_COUNTS2  32
#define WS_OFFSETS  64
#define WS_ETOK     128
#define WS_ESCALE   (WS_ETOK + NENT*4)
#define WS_ACT      (WS_ESCALE + NENT*4)

// ---------------- routing ----------------
__global__ void route_count(const int* __restrict__ sel, int* __restrict__ counts) {
  int i = blockIdx.x*256 + threadIdx.x;
  if (i < NENT) atomicAdd(&counts[sel[i]], 1);
}

__global__ void route_scan(const int* __restrict__ counts, int* __restrict__ offsets) {
  if (threadIdx.x == 0) {
    int s = 0;
    for (int e = 0; e < NEXP; e++) { offsets[e] = s; s += counts[e]; }
    offsets[NEXP] = s;
  }
}

__global__ void route_fill(const int* __restrict__ sel, const float* __restrict__ scal,
                           const int* __restrict__ offsets, int* __restrict__ counts2,
                           int* __restrict__ etok, float* __restrict__ escale) {
  int i = blockIdx.x*256 + threadIdx.x;
  if (i < NENT) {
    int e = sel[i];
    int pos = offsets[e] + atomicAdd(&counts2[e], 1);
    etok[pos]   = i >> 1;     // TOPK == 2
    escale[pos] = scal[i];
  }
}

// ---------------- grouped GEMM config ----------------
// BM=64: with nt~256/expert this gives 4 m-tiles/expert -> 4x the active
// blocks of the BM=128 variant (R1 was 1 block/CU, latency-bound at
// MfmaUtil 2%). BK=64: halves barrier count, 8-16 MFMA per K-iter.
#define BM 64
#define BN 64
#define BK 64
#define LSTR 72         // 64 + 8 pad bf16 (144B row stride, 16B aligned, ~2-way banks)
#define KSPLIT2 2       // split-K for gemm2 (epilogue is atomic anyway)

// GEMM1: act = silu(x@w1g^T + b1g) * (x@w1l^T + b1l), per expert, gathered tokens.
__global__ __launch_bounds__(256, 3) void gemm1_kernel(
    const float* __restrict__ hidden, const float* __restrict__ w1,
    const float* __restrict__ b1, const int* __restrict__ offsets,
    const int* __restrict__ etok, bf16_t* __restrict__ act)
{
  const int e   = blockIdx.z;
  const int off = offsets[e];
  const int nt  = offsets[e+1] - off;
  const int m0  = blockIdx.y * BM;
  if (m0 >= nt) return;
  const int n0  = blockIdx.x * BN;

  __shared__ bf16_t As[BM*LSTR];
  __shared__ bf16_t Bg[BN*LSTR];
  __shared__ bf16_t Bl[BN*LSTR];

  const int tid  = threadIdx.x;
  const int row  = tid >> 2;          // 0..63
  const int seg  = (tid & 3) * 16;    // 0,16,32,48 (fp32 elems)

  int aent = m0 + row; if (aent > nt-1) aent = nt-1;   // clamp; masked in epilogue
  const int atok = etok[off + aent];
  const float* aptr = hidden + (size_t)atok*HDIM + seg;
  const float* gptr = w1 + ((size_t)e*2*FDIM + (size_t)(n0 + row))*HDIM + seg;
  const float* lptr = gptr + (size_t)FDIM*HDIM;

  const int wave = tid >> 6, lane = tid & 63;
  const int wr = wave >> 1, wc = wave & 1;
  const int quad = lane >> 4, lr = lane & 15;

  float4 a4[4], g4[4], l4[4];
  {
    const float4* p;
    p = (const float4*)aptr; a4[0]=p[0]; a4[1]=p[1]; a4[2]=p[2]; a4[3]=p[3];
    p = (const float4*)gptr; g4[0]=p[0]; g4[1]=p[1]; g4[2]=p[2]; g4[3]=p[3];
    p = (const float4*)lptr; l4[0]=p[0]; l4[1]=p[1]; l4[2]=p[2]; l4[3]=p[3];
  }

  f32x4 accg[2][2] = {};
  f32x4 accl[2][2] = {};

  for (int k0 = 0; k0 < HDIM; k0 += BK) {
    __syncthreads();   // prior iteration's fragment reads complete
    {
      bf16_t* dst = &As[row*LSTR + seg];
      bf16x8 v;
      v[0]=(bf16_t)a4[0].x; v[1]=(bf16_t)a4[0].y; v[2]=(bf16_t)a4[0].z; v[3]=(bf16_t)a4[0].w;
      v[4]=(bf16_t)a4[1].x; v[5]=(bf16_t)a4[1].y; v[6]=(bf16_t)a4[1].z; v[7]=(bf16_t)a4[1].w;
      *(bf16x8*)dst = v;
      v[0]=(bf16_t)a4[2].x; v[1]=(bf16_t)a4[2].y; v[2]=(bf16_t)a4[2].z; v[3]=(bf16_t)a4[2].w;
      v[4]=(bf16_t)a4[3].x; v[5]=(bf16_t)a4[3].y; v[6]=(bf16_t)a4[3].z; v[7]=(bf16_t)a4[3].w;
      *(bf16x8*)(dst+8) = v;
      dst = &Bg[row*LSTR + seg];
      v[0]=(bf16_t)g4[0].x; v[1]=(bf16_t)g4[0].y; v[2]=(bf16_t)g4[0].z; v[3]=(bf16_t)g4[0].w;
      v[4]=(bf16_t)g4[1].x; v[5]=(bf16_t)g4[1].y; v[6]=(bf16_t)g4[1].z; v[7]=(bf16_t)g4[1].w;
      *(bf16x8*)dst = v;
      v[0]=(bf16_t)g4[2].x; v[1]=(bf16_t)g4[2].y; v[2]=(bf16_t)g4[2].z; v[3]=(bf16_t)g4[2].w;
      v[4]=(bf16_t)g4[3].x; v[5]=(bf16_t)g4[3].y; v[6]=(bf16_t)g4[3].z; v[7]=(bf16_t)g4[3].w;
      *(bf16x8*)(dst+8) = v;
      dst = &Bl[row*LSTR + seg];
      v[0]=(bf16_t)l4[0].x; v[1]=(bf16_t)l4[0].y; v[2]=(bf16_t)l4[0].z; v[3]=(bf16_t)l4[0].w;
      v[4]=(bf16_t)l4[1].x; v[5]=(bf16_t)l4[1].y; v[6]=(bf16_t)l4[1].z; v[7]=(bf16_t)l4[1].w;
      *(bf16x8*)dst = v;
      v[0]=(bf16_t)l4[2].x; v[1]=(bf16_t)l4[2].y; v[2]=(bf16_t)l4[2].z; v[3]=(bf16_t)l4[2].w;
      v[4]=(bf16_t)l4[3].x; v[5]=(bf16_t)l4[3].y; v[6]=(bf16_t)l4[3].z; v[7]=(bf16_t)l4[3].w;
      *(bf16x8*)(dst+8) = v;
    }
    __syncthreads();

    // prefetch next K-tile into registers (latency overlaps MFMA below)
    if (k0 + BK < HDIM) {
      const float4* p;
      p = (const float4*)(aptr + k0 + BK); a4[0]=p[0]; a4[1]=p[1]; a4[2]=p[2]; a4[3]=p[3];
      p = (const float4*)(gptr + k0 + BK); g4[0]=p[0]; g4[1]=p[1]; g4[2]=p[2]; g4[3]=p[3];
      p = (const float4*)(lptr + k0 + BK); l4[0]=p[0]; l4[1]=p[1]; l4[2]=p[2]; l4[3]=p[3];
    }

    #pragma unroll
    for (int kk = 0; kk < BK; kk += 32) {
      bf16x8 af[2], gf[2], lf[2];
      #pragma unroll
      for (int i = 0; i < 2; i++)
        af[i] = *(const bf16x8*)&As[(wr*32 + i*16 + lr)*LSTR + kk + quad*8];
      #pragma unroll
      for (int j = 0; j < 2; j++) {
        gf[j] = *(const bf16x8*)&Bg[(wc*32 + j*16 + lr)*LSTR + kk + quad*8];
        lf[j] = *(const bf16x8*)&Bl[(wc*32 + j*16 + lr)*LSTR + kk + quad*8];
      }
      #pragma unroll
      for (int i = 0; i < 2; i++)
        #pragma unroll
        for (int j = 0; j < 2; j++) {
          accg[i][j] = __builtin_amdgcn_mfma_f32_16x16x32_bf16(af[i], gf[j], accg[i][j], 0, 0, 0);
          accl[i][j] = __builtin_amdgcn_mfma_f32_16x16x32_bf16(af[i], lf[j], accl[i][j], 0, 0, 0);
        }
    }
  }

  // epilogue: bias + silu(gate)*lin -> act (bf16)
  #pragma unroll
  for (int j = 0; j < 2; j++) {
    const int f = n0 + wc*32 + j*16 + lr;
    const float bg_ = b1[e*2*FDIM + f];
    const float bl_ = b1[e*2*FDIM + FDIM + f];
    #pragma unroll
    for (int i = 0; i < 2; i++) {
      #pragma unroll
      for (int r = 0; r < 4; r++) {
        const int m = wr*32 + i*16 + quad*4 + r;
        if (m0 + m < nt) {
          const float g = accg[i][j][r] + bg_;
          const float l = accl[i][j][r] + bl_;
          const float s = g / (1.f + __expf(-g)) * l;
          act[(size_t)(off + m0 + m)*FDIM + f] = (bf16_t)s;
        }
      }
    }
  }
}

// GEMM2: y = act @ w2^T + b2; out[token] += scale * y  (atomic, split-K)
__global__ __launch_bounds__(256, 4) void gemm2_kernel(
    const bf16_t* __restrict__ act, const float* __restrict__ w2,
    const float* __restrict__ b2, const int* __restrict__ offsets,
    const int* __restrict__ etok, const float* __restrict__ escale,
    float* __restrict__ out)
{
  const int e   = blockIdx.z;
  const int off = offsets[e];
  const int nt  = offsets[e+1] - off;
  const int m0  = blockIdx.y * BM;
  if (m0 >= nt) return;
  const int n0  = (blockIdx.x >> 1) * BN;
  const int kc  = blockIdx.x & 1;            // split-K chunk
  const int kbeg = kc * (FDIM / KSPLIT2);
  const int kend = kbeg + FDIM / KSPLIT2;

  __shared__ bf16_t As[BM*LSTR];
  __shared__ bf16_t Bs[BN*LSTR];

  const int tid = threadIdx.x;
  const int row = tid >> 2;
  const int seg = (tid & 3) * 16;

  int aent = m0 + row; if (aent > nt-1) aent = nt-1;
  const bf16_t* aptr = act + (size_t)(off + aent)*FDIM + seg;
  const float*  bptr = w2 + ((size_t)e*HDIM + (size_t)(n0 + row))*FDIM + seg;

  const int wave = tid >> 6, lane = tid & 63;
  const int wr = wave >> 1, wc = wave & 1;
  const int quad = lane >> 4, lr = lane & 15;

  uint4  a0, a1;
  float4 b4[4];
  {
    const uint4* ap = (const uint4*)(aptr + kbeg);
    a0 = ap[0]; a1 = ap[1];
    const float4* bp = (const float4*)(bptr + kbeg);
    b4[0]=bp[0]; b4[1]=bp[1]; b4[2]=bp[2]; b4[3]=bp[3];
  }

  f32x4 acc[2][2] = {};

  for (int k0 = kbeg; k0 < kend; k0 += BK) {
    __syncthreads();
    {
      bf16_t* dst = &As[row*LSTR + seg];
      *(uint4*)dst = a0;
      *(uint4*)(dst+8) = a1;
      dst = &Bs[row*LSTR + seg];
      bf16x8 v;
      v[0]=(bf16_t)b4[0].x; v[1]=(bf16_t)b4[0].y; v[2]=(bf16_t)b4[0].z; v[3]=(bf16_t)b4[0].w;
      v[4]=(bf16_t)b4[1].x; v[5]=(bf16_t)b4[1].y; v[6]=(bf16_t)b4[1].z; v[7]=(bf16_t)b4[1].w;
      *(bf16x8*)dst = v;
      v[0]=(bf16_t)b4[2].x; v[1]=(bf16_t)b4[2].y; v[2]=(bf16_t)b4[2].z; v[3]=(bf16_t)b4[2].w;
      v[4]=(bf16_t)b4[3].x; v[5]=(bf16_t)b4[3].y; v[6]=(bf16_t)b4[3].z; v[7]=(bf16_t)b4[3].w;
      *(bf16x8*)(dst+8) = v;
    }
    __syncthreads();

    if (k0 + BK < kend) {
      const uint4* ap = (const uint4*)(aptr + k0 + BK);
      a0 = ap[0]; a1 = ap[1];
      const float4* bp = (const float4*)(bptr + k0 + BK);
      b4[0]=bp[0]; b4[1]=bp[1]; b4[2]=bp[2]; b4[3]=bp[3];
    }

    #pragma unroll
    for (int kk = 0; kk < BK; kk += 32) {
      bf16x8 af[2], bf[2];
      #pragma unroll
      for (int i = 0; i < 2; i++)
        af[i] = *(const bf16x8*)&As[(wr*32 + i*16 + lr)*LSTR + kk + quad*8];
      #pragma unroll
      for (int j = 0; j < 2; j++)
        bf[j] = *(const bf16x8*)&Bs[(wc*32 + j*16 + lr)*LSTR + kk + quad*8];
      #pragma unroll
      for (int i = 0; i < 2; i++)
        #pragma unroll
        for (int j = 0; j < 2; j++)
          acc[i][j] = __builtin_amdgcn_mfma_f32_16x16x32_bf16(af[i], bf[j], acc[i][j], 0, 0, 0);
    }
  }

  // epilogue: + b2 (chunk 0 only), scale, atomic scatter-add into out
  #pragma unroll
  for (int i = 0; i < 2; i++) {
    #pragma unroll
    for (int r = 0; r < 4; r++) {
      const int m = wr*32 + i*16 + quad*4 + r;
      if (m0 + m < nt) {
        const int slot = off + m0 + m;
        const int t    = etok[slot];
        const float s  = escale[slot];
        #pragma unroll
        for (int j = 0; j < 2; j++) {
          const int n = n0 + wc*32 + j*16 + lr;
          float v = acc[i][j][r];
          if (kc == 0) v += b2[e*HDIM + n];
          atomicAdd(&out[(size_t)t*HDIM + n], s * v);
        }
      }
    }
  }
}

extern "C" void kernel_launch(void* const* d_in, const int* in_sizes, int n_in,
                              void* d_out, int out_size, void* d_ws, size_t ws_size,
                              hipStream_t stream) {
  const float* hidden = (const float*)d_in[0];
  const int*   sel    = (const int*)d_in[1];
  const float* scal   = (const float*)d_in[2];
  const float* w1     = (const float*)d_in[3];
  const float* b1     = (const float*)d_in[4];
  const float* w2     = (const float*)d_in[5];
  const float* b2     = (const float*)d_in[6];
  float* out = (float*)d_out;

  char* ws = (char*)d_ws;
  int*    counts  = (int*)(ws + WS_COUNTS);
  int*    counts2 = (int*)(ws + WS_COUNTS2);
  int*    offsets = (int*)(ws + WS_OFFSETS);
  int*    etok    = (int*)(ws + WS_ETOK);
  float*  escale  = (float*)(ws + WS_ESCALE);
  bf16_t* act     = (bf16_t*)(ws + WS_ACT);

  hipMemsetAsync(ws, 0, 64, stream);
  hipMemsetAsync(d_out, 0, (size_t)out_size * sizeof(float), stream);

  route_count<<<NENT/256, 256, 0, stream>>>(sel, counts);
  route_scan <<<1, 64, 0, stream>>>(counts, offsets);
  route_fill <<<NENT/256, 256, 0, stream>>>(sel, scal, offsets, counts2, etok, escale);

  gemm1_kernel<<<dim3(FDIM/BN, NENT/BM, NEXP), 256, 0, stream>>>(hidden, w1, b1, offsets, etok, act);
  gemm2_kernel<<<dim3((HDIM/BN)*KSPLIT2, NENT/BM, NEXP), 256, 0, stream>>>(act, w2, b2, offsets, etok, escale, out);
}

// Round 3
// 338.036 us; speedup vs baseline: 1.4638x; 1.0690x over previous
//
#include <hip/hip_runtime.h>
#include <hip/hip_bf16.h>
#include <cstdint>
#include <cstddef>

// Problem constants (fixed by the reference)
#define TDIM 1024
#define HDIM 1024
#define FDIM 2048
#define NEXP 8
#define NENT 2048   // T * K

typedef __bf16 bf16_t;
typedef __bf16 bf16x4 __attribute__((ext_vector_type(4)));
typedef __bf16 bf16x8 __attribute__((ext_vector_type(8)));
typedef float  f32x4  __attribute__((ext_vector_type(4)));

#define W1_ELEMS ((size_t)NEXP*2*FDIM*HDIM)  // 33554432
#define W2_ELEMS ((size_t)NEXP*HDIM*FDIM)    // 16777216
#define H_ELEMS  ((size_t)TDIM*HDIM)         // 1048576

// ---------------- bf16-path workspace layout (bytes) ----------------
#define WB_OFFSETS 0                                   // int[16]
#define WB_ETOK    64
#define WB_ESCALE  (WB_ETOK + NENT*4)                  // 8256
#define WB_ACT     16512                               // bf16[NENT][FDIM] = 8 MB
#define WB_W1      (WB_ACT + (size_t)NENT*FDIM*2)      // 16793728
#define WB_W2      (WB_W1 + W1_ELEMS*2)                // 83902592
#define WB_H       (WB_W2 + W2_ELEMS*2)                // 117457024
#define WB_END     (WB_H + H_ELEMS*2)                  // 119554176

// ---------------- fallback (fp32-staging) ws layout ----------------
#define WS_COUNTS   0
#define WS_COUNTS2  32
#define WS_OFFSETS  64
#define WS_ETOK     128
#define WS_ESCALE   (WS_ETOK + NENT*4)
#define WS_ACT      (WS_ESCALE + NENT*4)

__device__ __forceinline__ void gload16(const void* g, void* l) {
  __builtin_amdgcn_global_load_lds((const __attribute__((address_space(1))) void*)g,
                                   (__attribute__((address_space(3))) void*)l, 16, 0, 0);
}

// ---------------- routing (single block, one launch) ----------------
__global__ void route_all(const int* __restrict__ sel, const float* __restrict__ scal,
                          int* __restrict__ offsets, int* __restrict__ etok,
                          float* __restrict__ escale) {
  __shared__ int cnt[NEXP], cnt2[NEXP], offs[NEXP+1];
  const int t = threadIdx.x;    // 256 threads, 8 entries each
  if (t < NEXP) { cnt[t] = 0; cnt2[t] = 0; }
  __syncthreads();
  int e8[8];
  #pragma unroll
  for (int q = 0; q < 8; q++) {
    int i = t*8 + q;
    e8[q] = sel[i];
    atomicAdd(&cnt[e8[q]], 1);
  }
  __syncthreads();
  if (t == 0) {
    int s = 0;
    for (int e = 0; e < NEXP; e++) { offs[e] = s; offsets[e] = s; s += cnt[e]; }
    offs[NEXP] = s; offsets[NEXP] = s;
  }
  __syncthreads();
  #pragma unroll
  for (int q = 0; q < 8; q++) {
    int i = t*8 + q;
    int e = e8[q];
    int pos = offs[e] + atomicAdd(&cnt2[e], 1);
    etok[pos]   = i >> 1;       // TOPK == 2
    escale[pos] = scal[i];
  }
}

// ---------------- fp32 -> bf16 pre-conversion (w1, w2, hidden) ----------------
#define CV_GROUPS ((W1_ELEMS + W2_ELEMS + H_ELEMS) / 8)   // 6422528
__global__ void convert_kernel(const float* __restrict__ w1, const float* __restrict__ w2,
                               const float* __restrict__ h,
                               bf16_t* __restrict__ w1bf, bf16_t* __restrict__ w2bf,
                               bf16_t* __restrict__ hbf) {
  size_t idx = ((size_t)blockIdx.x*256 + threadIdx.x) * 8;
  const float* src; bf16_t* dst;
  if (idx < W1_ELEMS)                { src = w1 + idx;                       dst = w1bf + idx; }
  else if (idx < W1_ELEMS+W2_ELEMS)  { size_t j = idx - W1_ELEMS;            src = w2 + j; dst = w2bf + j; }
  else                               { size_t j = idx - W1_ELEMS - W2_ELEMS; src = h  + j; dst = hbf  + j; }
  float4 v0 = ((const float4*)src)[0];
  float4 v1 = ((const float4*)src)[1];
  bf16x8 o;
  o[0]=(bf16_t)v0.x; o[1]=(bf16_t)v0.y; o[2]=(bf16_t)v0.z; o[3]=(bf16_t)v0.w;
  o[4]=(bf16_t)v1.x; o[5]=(bf16_t)v1.y; o[6]=(bf16_t)v1.z; o[7]=(bf16_t)v1.w;
  *(bf16x8*)dst = o;
}

// ---------------- bf16 grouped GEMMs (global_load_lds, swizzled LDS) ----------------
// Tile 64x64x64, 4 waves, each wave 32x32 (2x2 16x16x32 frags).
// LDS layout: [row][seg] where seg s holds global seg s ^ (row & 7) (16B units).

// GEMM1: act = silu(x@w1g^T + b1g) * (x@w1l^T + b1l)
__global__ __launch_bounds__(256, 4) void gemm1_bf(
    const bf16_t* __restrict__ hbf, const bf16_t* __restrict__ w1bf,
    const float* __restrict__ b1, const int* __restrict__ offsets,
    const int* __restrict__ etok, bf16_t* __restrict__ act)
{
  const int e   = blockIdx.z;
  const int off = offsets[e];
  const int nt  = offsets[e+1] - off;
  const int m0  = blockIdx.y * 64;
  if (m0 >= nt) return;
  const int n0  = blockIdx.x * 64;

  __shared__ __align__(16) bf16_t As[64*64];
  __shared__ __align__(16) bf16_t Bg[64*64];
  __shared__ __align__(16) bf16_t Bl[64*64];

  const int tid  = threadIdx.x;
  const int w    = tid >> 6, lane = tid & 63;
  const int quad = lane >> 4, lr = lane & 15;
  const int wr   = w >> 1,  wc = w & 1;

  // loader mapping: inst i covers tile rows w*16+i*8 .. +8; 8 segs of 16B per row
  const int lrow = lane >> 3;                 // row-within-8 == (tile_row & 7)
  const int ssrc = ((lane & 7) ^ lrow) * 8;   // swizzled source col (bf16 elems)

  const bf16_t *asrc[2], *gsrc[2], *lsrc[2];
  bf16_t *adst[2], *gdst[2], *ldst[2];
  #pragma unroll
  for (int i = 0; i < 2; i++) {
    const int r = w*16 + i*8 + lrow;
    int aent = m0 + r; if (aent > nt-1) aent = nt-1;      // clamp; masked in epilogue
    const int tok = etok[off + aent];
    asrc[i] = hbf  + (size_t)tok*HDIM + ssrc;
    gsrc[i] = w1bf + ((size_t)e*2*FDIM + n0 + r)*HDIM + ssrc;
    lsrc[i] = gsrc[i] + (size_t)FDIM*HDIM;
    adst[i] = &As[(w*16 + i*8)*64];
    gdst[i] = &Bg[(w*16 + i*8)*64];
    ldst[i] = &Bl[(w*16 + i*8)*64];
  }

  f32x4 accg[2][2] = {}, accl[2][2] = {};

  for (int k0 = 0; k0 < HDIM; k0 += 64) {
    __syncthreads();                 // prior iter's frag reads complete
    #pragma unroll
    for (int i = 0; i < 2; i++) {
      gload16(asrc[i] + k0, adst[i]);
      gload16(gsrc[i] + k0, gdst[i]);
      gload16(lsrc[i] + k0, ldst[i]);
    }
    __syncthreads();                 // drains vmcnt -> LDS tiles ready

    #pragma unroll
    for (int kk = 0; kk < 64; kk += 32) {
      const int g = quad + (kk >> 3);          // global seg wanted
      bf16x8 af[2], gf[2], lf[2];
      #pragma unroll
      for (int i = 0; i < 2; i++) {
        const int m = wr*32 + i*16 + lr;
        af[i] = *(const bf16x8*)&As[m*64 + (g ^ (m & 7))*8];
      }
      #pragma unroll
      for (int j = 0; j < 2; j++) {
        const int n = wc*32 + j*16 + lr;
        gf[j] = *(const bf16x8*)&Bg[n*64 + (g ^ (n & 7))*8];
        lf[j] = *(const bf16x8*)&Bl[n*64 + (g ^ (n & 7))*8];
      }
      #pragma unroll
      for (int i = 0; i < 2; i++)
        #pragma unroll
        for (int j = 0; j < 2; j++) {
          accg[i][j] = __builtin_amdgcn_mfma_f32_16x16x32_bf16(af[i], gf[j], accg[i][j], 0, 0, 0);
          accl[i][j] = __builtin_amdgcn_mfma_f32_16x16x32_bf16(af[i], lf[j], accl[i][j], 0, 0, 0);
        }
    }
  }

  // epilogue: bias + silu(gate)*lin -> act (bf16)
  #pragma unroll
  for (int j = 0; j < 2; j++) {
    const int f = n0 + wc*32 + j*16 + lr;
    const float bg_ = b1[e*2*FDIM + f];
    const float bl_ = b1[e*2*FDIM + FDIM + f];
    #pragma unroll
    for (int i = 0; i < 2; i++) {
      #pragma unroll
      for (int r = 0; r < 4; r++) {
        const int m = wr*32 + i*16 + quad*4 + r;
        if (m0 + m < nt) {
          const float g = accg[i][j][r] + bg_;
          const float l = accl[i][j][r] + bl_;
          const float s = g / (1.f + __expf(-g)) * l;
          act[(size_t)(off + m0 + m)*FDIM + f] = (bf16_t)s;
        }
      }
    }
  }
}

// GEMM2: y = act @ w2^T + b2; out[token] += scale * y  (atomic, split-K x2)
__global__ __launch_bounds__(256, 4) void gemm2_bf(
    const bf16_t* __restrict__ act, const bf16_t* __restrict__ w2bf,
    const float* __restrict__ b2, const int* __restrict__ offsets,
    const int* __restrict__ etok, const float* __restrict__ escale,
    float* __restrict__ out)
{
  const int e   = blockIdx.z;
  const int off = offsets[e];
  const int nt  = offsets[e+1] - off;
  const int m0  = blockIdx.y * 64;
  if (m0 >= nt) return;
  const int n0  = (blockIdx.x >> 1) * 64;
  const int kc  = blockIdx.x & 1;
  const int kbeg = kc * (FDIM/2);
  const int kend = kbeg + FDIM/2;

  __shared__ __align__(16) bf16_t As[64*64];
  __shared__ __align__(16) bf16_t Bs[64*64];

  const int tid  = threadIdx.x;
  const int w    = tid >> 6, lane = tid & 63;
  const int quad = lane >> 4, lr = lane & 15;
  const int wr   = w >> 1,  wc = w & 1;

  const int lrow = lane >> 3;
  const int ssrc = ((lane & 7) ^ lrow) * 8;

  const bf16_t *asrc[2], *bsrc[2];
  bf16_t *adst[2], *bdst[2];
  #pragma unroll
  for (int i = 0; i < 2; i++) {
    const int r = w*16 + i*8 + lrow;
    int aent = m0 + r; if (aent > nt-1) aent = nt-1;
    asrc[i] = act  + (size_t)(off + aent)*FDIM + ssrc;
    bsrc[i] = w2bf + ((size_t)e*HDIM + n0 + r)*FDIM + ssrc;
    adst[i] = &As[(w*16 + i*8)*64];
    bdst[i] = &Bs[(w*16 + i*8)*64];
  }

  f32x4 acc[2][2] = {};

  for (int k0 = kbeg; k0 < kend; k0 += 64) {
    __syncthreads();
    #pragma unroll
    for (int i = 0; i < 2; i++) {
      gload16(asrc[i] + k0, adst[i]);
      gload16(bsrc[i] + k0, bdst[i]);
    }
    __syncthreads();

    #pragma unroll
    for (int kk = 0; kk < 64; kk += 32) {
      const int g = quad + (kk >> 3);
      bf16x8 af[2], bfr[2];
      #pragma unroll
      for (int i = 0; i < 2; i++) {
        const int m = wr*32 + i*16 + lr;
        af[i] = *(const bf16x8*)&As[m*64 + (g ^ (m & 7))*8];
      }
      #pragma unroll
      for (int j = 0; j < 2; j++) {
        const int n = wc*32 + j*16 + lr;
        bfr[j] = *(const bf16x8*)&Bs[n*64 + (g ^ (n & 7))*8];
      }
      #pragma unroll
      for (int i = 0; i < 2; i++)
        #pragma unroll
        for (int j = 0; j < 2; j++)
          acc[i][j] = __builtin_amdgcn_mfma_f32_16x16x32_bf16(af[i], bfr[j], acc[i][j], 0, 0, 0);
    }
  }

  #pragma unroll
  for (int i = 0; i < 2; i++) {
    #pragma unroll
    for (int r = 0; r < 4; r++) {
      const int m = wr*32 + i*16 + quad*4 + r;
      if (m0 + m < nt) {
        const int slot = off + m0 + m;
        const int t    = etok[slot];
        const float s  = escale[slot];
        #pragma unroll
        for (int j = 0; j < 2; j++) {
          const int n = n0 + wc*32 + j*16 + lr;
          float v = acc[i][j][r];
          if (kc == 0) v += b2[e*HDIM + n];
          atomicAdd(&out[(size_t)t*HDIM + n], s * v);
        }
      }
    }
  }
}

// =================== fallback path (fp32 staging, R2 kernels) ===================
#define BM 64
#define BN 64
#define BK 64
#define LSTR 72
#define KSPLIT2 2

__global__ void route_count(const int* __restrict__ sel, int* __restrict__ counts) {
  int i = blockIdx.x*256 + threadIdx.x;
  if (i < NENT) atomicAdd(&counts[sel[i]], 1);
}
__global__ void route_scan(const int* __restrict__ counts, int* __restrict__ offsets) {
  if (threadIdx.x == 0) {
    int s = 0;
    for (int e = 0; e < NEXP; e++) { offsets[e] = s; s += counts[e]; }
    offsets[NEXP] = s;
  }
}
__global__ void route_fill(const int* __restrict__ sel, const float* __restrict__ scal,
                           const int* __restrict__ offsets, int* __restrict__ counts2,
                           int* __restrict__ etok, float* __restrict__ escale) {
  int i = blockIdx.x*256 + threadIdx.x;
  if (i < NENT) {
    int e = sel[i];
    int pos = offsets[e] + atomicAdd(&counts2[e], 1);
    etok[pos]   = i >> 1;
    escale[pos] = scal[i];
  }
}

__global__ __launch_bounds__(256, 3) void gemm1_kernel(
    const float* __restrict__ hidden, const float* __restrict__ w1,
    const float* __restrict__ b1, const int* __restrict__ offsets,
    const int* __restrict__ etok, bf16_t* __restrict__ act)
{
  const int e   = blockIdx.z;
  const int off = offsets[e];
  const int nt  = offsets[e+1] - off;
  const int m0  = blockIdx.y * BM;
  if (m0 >= nt) return;
  const int n0  = blockIdx.x * BN;

  __shared__ bf16_t As[BM*LSTR];
  __shared__ bf16_t Bg[BN*LSTR];
  __shared__ bf16_t Bl[BN*LSTR];

  const int tid  = threadIdx.x;
  const int row  = tid >> 2;
  const int seg  = (tid & 3) * 16;

  int aent = m0 + row; if (aent > nt-1) aent = nt-1;
  const int atok = etok[off + aent];
  const float* aptr = hidden + (size_t)atok*HDIM + seg;
  const float* gptr = w1 + ((size_t)e*2*FDIM + (size_t)(n0 + row))*HDIM + seg;
  const float* lptr = gptr + (size_t)FDIM*HDIM;

  const int wave = tid >> 6, lane = tid & 63;
  const int wr = wave >> 1, wc = wave & 1;
  const int quad = lane >> 4, lr = lane & 15;

  float4 a4[4], g4[4], l4[4];
  {
    const float4* p;
    p = (const float4*)aptr; a4[0]=p[0]; a4[1]=p[1]; a4[2]=p[2]; a4[3]=p[3];
    p = (const float4*)gptr; g4[0]=p[0]; g4[1]=p[1]; g4[2]=p[2]; g4[3]=p[3];
    p = (const float4*)lptr; l4[0]=p[0]; l4[1]=p[1]; l4[2]=p[2]; l4[3]=p[3];
  }

  f32x4 accg[2][2] = {};
  f32x4 accl[2][2] = {};

  for (int k0 = 0; k0 < HDIM; k0 += BK) {
    __syncthreads();
    {
      bf16_t* dst = &As[row*LSTR + seg];
      bf16x8 v;
      v[0]=(bf16_t)a4[0].x; v[1]=(bf16_t)a4[0].y; v[2]=(bf16_t)a4[0].z; v[3]=(bf16_t)a4[0].w;
      v[4]=(bf16_t)a4[1].x; v[5]=(bf16_t)a4[1].y; v[6]=(bf16_t)a4[1].z; v[7]=(bf16_t)a4[1].w;
      *(bf16x8*)dst = v;
      v[0]=(bf16_t)a4[2].x; v[1]=(bf16_t)a4[2].y; v[2]=(bf16_t)a4[2].z; v[3]=(bf16_t)a4[2].w;
      v[4]=(bf16_t)a4[3].x; v[5]=(bf16_t)a4[3].y; v[6]=(bf16_t)a4[3].z; v[7]=(bf16_t)a4[3].w;
      *(bf16x8*)(dst+8) = v;
      dst = &Bg[row*LSTR + seg];
      v[0]=(bf16_t)g4[0].x; v[1]=(bf16_t)g4[0].y; v[2]=(bf16_t)g4[0].z; v[3]=(bf16_t)g4[0].w;
      v[4]=(bf16_t)g4[1].x; v[5]=(bf16_t)g4[1].y; v[6]=(bf16_t)g4[1].z; v[7]=(bf16_t)g4[1].w;
      *(bf16x8*)dst = v;
      v[0]=(bf16_t)g4[2].x; v[1]=(bf16_t)g4[2].y; v[2]=(bf16_t)g4[2].z; v[3]=(bf16_t)g4[2].w;
      v[4]=(bf16_t)g4[3].x; v[5]=(bf16_t)g4[3].y; v[6]=(bf16_t)g4[3].z; v[7]=(bf16_t)g4[3].w;
      *(bf16x8*)(dst+8) = v;
      dst = &Bl[row*LSTR + seg];
      v[0]=(bf16_t)l4[0].x; v[1]=(bf16_t)l4[0].y; v[2]=(bf16_t)l4[0].z; v[3]=(bf16_t)l4[0].w;
      v[4]=(bf16_t)l4[1].x; v[5]=(bf16_t)l4[1].y; v[6]=(bf16_t)l4[1].z; v[7]=(bf16_t)l4[1].w;
      *(bf16x8*)dst = v;
      v[0]=(bf16_t)l4[2].x; v[1]=(bf16_t)l4[2].y; v[2]=(bf16_t)l4[2].z; v[3]=(bf16_t)l4[2].w;
      v[4]=(bf16_t)l4[3].x; v[5]=(bf16_t)l4[3].y; v[6]=(bf16_t)l4[3].z; v[7]=(bf16_t)l4[3].w;
      *(bf16x8*)(dst+8) = v;
    }
    __syncthreads();

    if (k0 + BK < HDIM) {
      const float4* p;
      p = (const float4*)(aptr + k0 + BK); a4[0]=p[0]; a4[1]=p[1]; a4[2]=p[2]; a4[3]=p[3];
      p = (const float4*)(gptr + k0 + BK); g4[0]=p[0]; g4[1]=p[1]; g4[2]=p[2]; g4[3]=p[3];
      p = (const float4*)(lptr + k0 + BK); l4[0]=p[0]; l4[1]=p[1]; l4[2]=p[2]; l4[3]=p[3];
    }

    #pragma unroll
    for (int kk = 0; kk < BK; kk += 32) {
      bf16x8 af[2], gf[2], lf[2];
      #pragma unroll
      for (int i = 0; i < 2; i++)
        af[i] = *(const bf16x8*)&As[(wr*32 + i*16 + lr)*LSTR + kk + quad*8];
      #pragma unroll
      for (int j = 0; j < 2; j++) {
        gf[j] = *(const bf16x8*)&Bg[(wc*32 + j*16 + lr)*LSTR + kk + quad*8];
        lf[j] = *(const bf16x8*)&Bl[(wc*32 + j*16 + lr)*LSTR + kk + quad*8];
      }
      #pragma unroll
      for (int i = 0; i < 2; i++)
        #pragma unroll
        for (int j = 0; j < 2; j++) {
          accg[i][j] = __builtin_amdgcn_mfma_f32_16x16x32_bf16(af[i], gf[j], accg[i][j], 0, 0, 0);
          accl[i][j] = __builtin_amdgcn_mfma_f32_16x16x32_bf16(af[i], lf[j], accl[i][j], 0, 0, 0);
        }
    }
  }

  #pragma unroll
  for (int j = 0; j < 2; j++) {
    const int f = n0 + wc*32 + j*16 + lr;
    const float bg_ = b1[e*2*FDIM + f];
    const float bl_ = b1[e*2*FDIM + FDIM + f];
    #pragma unroll
    for (int i = 0; i < 2; i++) {
      #pragma unroll
      for (int r = 0; r < 4; r++) {
        const int m = wr*32 + i*16 + quad*4 + r;
        if (m0 + m < nt) {
          const float g = accg[i][j][r] + bg_;
          const float l = accl[i][j][r] + bl_;
          const float s = g / (1.f + __expf(-g)) * l;
          act[(size_t)(off + m0 + m)*FDIM + f] = (bf16_t)s;
        }
      }
    }
  }
}

__global__ __launch_bounds__(256, 4) void gemm2_kernel(
    const bf16_t* __restrict__ act, const float* __restrict__ w2,
    const float* __restrict__ b2, const int* __restrict__ offsets,
    const int* __restrict__ etok, const float* __restrict__ escale,
    float* __restrict__ out)
{
  const int e   = blockIdx.z;
  const int off = offsets[e];
  const int nt  = offsets[e+1] - off;
  const int m0  = blockIdx.y * BM;
  if (m0 >= nt) return;
  const int n0  = (blockIdx.x >> 1) * BN;
  const int kc  = blockIdx.x & 1;
  const int kbeg = kc * (FDIM / KSPLIT2);
  const int kend = kbeg + FDIM / KSPLIT2;

  __shared__ bf16_t As[BM*LSTR];
  __shared__ bf16_t Bs[BN*LSTR];

  const int tid = threadIdx.x;
  const int row = tid >> 2;
  const int seg = (tid & 3) * 16;

  int aent = m0 + row; if (aent > nt-1) aent = nt-1;
  const bf16_t* aptr = act + (size_t)(off + aent)*FDIM + seg;
  const float*  bptr = w2 + ((size_t)e*HDIM + (size_t)(n0 + row))*FDIM + seg;

  const int wave = tid >> 6, lane = tid & 63;
  const int wr = wave >> 1, wc = wave & 1;
  const int quad = lane >> 4, lr = lane & 15;

  uint4  a0, a1;
  float4 b4[4];
  {
    const uint4* ap = (const uint4*)(aptr + kbeg);
    a0 = ap[0]; a1 = ap[1];
    const float4* bp = (const float4*)(bptr + kbeg);
    b4[0]=bp[0]; b4[1]=bp[1]; b4[2]=bp[2]; b4[3]=bp[3];
  }

  f32x4 acc[2][2] = {};

  for (int k0 = kbeg; k0 < kend; k0 += BK) {
    __syncthreads();
    {
      bf16_t* dst = &As[row*LSTR + seg];
      *(uint4*)dst = a0;
      *(uint4*)(dst+8) = a1;
      dst = &Bs[row*LSTR + seg];
      bf16x8 v;
      v[0]=(bf16_t)b4[0].x; v[1]=(bf16_t)b4[0].y; v[2]=(bf16_t)b4[0].z; v[3]=(bf16_t)b4[0].w;
      v[4]=(bf16_t)b4[1].x; v[5]=(bf16_t)b4[1].y; v[6]=(bf16_t)b4[1].z; v[7]=(bf16_t)b4[1].w;
      *(bf16x8*)dst = v;
      v[0]=(bf16_t)b4[2].x; v[1]=(bf16_t)b4[2].y; v[2]=(bf16_t)b4[2].z; v[3]=(bf16_t)b4[2].w;
      v[4]=(bf16_t)b4[3].x; v[5]=(bf16_t)b4[3].y; v[6]=(bf16_t)b4[3].z; v[7]=(bf16_t)b4[3].w;
      *(bf16x8*)(dst+8) = v;
    }
    __syncthreads();

    if (k0 + BK < kend) {
      const uint4* ap = (const uint4*)(aptr + k0 + BK);
      a0 = ap[0]; a1 = ap[1];
      const float4* bp = (const float4*)(bptr + k0 + BK);
      b4[0]=bp[0]; b4[1]=bp[1]; b4[2]=bp[2]; b4[3]=bp[3];
    }

    #pragma unroll
    for (int kk = 0; kk < BK; kk += 32) {
      bf16x8 af[2], bfr[2];
      #pragma unroll
      for (int i = 0; i < 2; i++)
        af[i] = *(const bf16x8*)&As[(wr*32 + i*16 + lr)*LSTR + kk + quad*8];
      #pragma unroll
      for (int j = 0; j < 2; j++)
        bfr[j] = *(const bf16x8*)&Bs[(wc*32 + j*16 + lr)*LSTR + kk + quad*8];
      #pragma unroll
      for (int i = 0; i < 2; i++)
        #pragma unroll
        for (int j = 0; j < 2; j++)
          acc[i][j] = __builtin_amdgcn_mfma_f32_16x16x32_bf16(af[i], bfr[j], acc[i][j], 0, 0, 0);
    }
  }

  #pragma unroll
  for (int i = 0; i < 2; i++) {
    #pragma unroll
    for (int r = 0; r < 4; r++) {
      const int m = wr*32 + i*16 + quad*4 + r;
      if (m0 + m < nt) {
        const int slot = off + m0 + m;
        const int t    = etok[slot];
        const float s  = escale[slot];
        #pragma unroll
        for (int j = 0; j < 2; j++) {
          const int n = n0 + wc*32 + j*16 + lr;
          float v = acc[i][j][r];
          if (kc == 0) v += b2[e*HDIM + n];
          atomicAdd(&out[(size_t)t*HDIM + n], s * v);
        }
      }
    }
  }
}

extern "C" void kernel_launch(void* const* d_in, const int* in_sizes, int n_in,
                              void* d_out, int out_size, void* d_ws, size_t ws_size,
                              hipStream_t stream) {
  const float* hidden = (const float*)d_in[0];
  const int*   sel    = (const int*)d_in[1];
  const float* scal   = (const float*)d_in[2];
  const float* w1     = (const float*)d_in[3];
  const float* b1     = (const float*)d_in[4];
  const float* w2     = (const float*)d_in[5];
  const float* b2     = (const float*)d_in[6];
  float* out = (float*)d_out;

  char* ws = (char*)d_ws;
  hipMemsetAsync(d_out, 0, (size_t)out_size * sizeof(float), stream);

  if (ws_size >= (size_t)WB_END) {
    // ---- bf16 path ----
    int*    offsets = (int*)(ws + WB_OFFSETS);
    int*    etok    = (int*)(ws + WB_ETOK);
    float*  escale  = (float*)(ws + WB_ESCALE);
    bf16_t* act     = (bf16_t*)(ws + WB_ACT);
    bf16_t* w1bf    = (bf16_t*)(ws + WB_W1);
    bf16_t* w2bf    = (bf16_t*)(ws + WB_W2);
    bf16_t* hbf     = (bf16_t*)(ws + WB_H);

    route_all<<<1, 256, 0, stream>>>(sel, scal, offsets, etok, escale);
    convert_kernel<<<(int)(CV_GROUPS/256), 256, 0, stream>>>(w1, w2, hidden, w1bf, w2bf, hbf);
    gemm1_bf<<<dim3(FDIM/64, NENT/64, NEXP), 256, 0, stream>>>(hbf, w1bf, b1, offsets, etok, act);
    gemm2_bf<<<dim3((HDIM/64)*2, NENT/64, NEXP), 256, 0, stream>>>(act, w2bf, b2, offsets, etok, escale, out);
  } else {
    // ---- fallback fp32-staging path ----
    int*    counts  = (int*)(ws + WS_COUNTS);
    int*    counts2 = (int*)(ws + WS_COUNTS2);
    int*    offsets = (int*)(ws + WS_OFFSETS);
    int*    etok    = (int*)(ws + WS_ETOK);
    float*  escale  = (float*)(ws + WS_ESCALE);
    bf16_t* act     = (bf16_t*)(ws + WS_ACT);

    hipMemsetAsync(ws, 0, 64, stream);
    route_count<<<NENT/256, 256, 0, stream>>>(sel, counts);
    route_scan <<<1, 64, 0, stream>>>(counts, offsets);
    route_fill <<<NENT/256, 256, 0, stream>>>(sel, scal, offsets, counts2, etok, escale);
    gemm1_kernel<<<dim3(FDIM/BN, NENT/BM, NEXP), 256, 0, stream>>>(hidden, w1, b1, offsets, etok, act);
    gemm2_kernel<<<dim3((HDIM/BN)*KSPLIT2, NENT/BM, NEXP), 256, 0, stream>>>(act, w2, b2, offsets, etok, escale, out);
  }
}